// Round 10
// baseline (198.373 us; speedup 1.0000x reference)
//
#include <hip/hip_runtime.h>
#include <hip/hip_bf16.h>
#include <cstdint>

typedef __bf16 bf16x8 __attribute__((ext_vector_type(8)));
typedef float  f32x4  __attribute__((ext_vector_type(4)));

#define BDIM 8192
#define KDIM 2048
#define NDIM 4096
#define HDIM 1024
#define LN_EPS 1e-6f
#define NT    (KDIM / 64)    // 32 K-tiles of BK=64
#define TOTA  ((long)BDIM * KDIM)
#define TOTB  ((long)NDIM * KDIM)

// ---------------------------------------------------------------------------
// Kernel 1: merged f32 -> bf16 convert + concat for A=[x|h] and Bt=[w_ih|w_hh].
// ---------------------------------------------------------------------------
__global__ __launch_bounds__(256) void cvt_all_kernel(
    const float* __restrict__ x, const float* __restrict__ h,
    const float* __restrict__ wih, const float* __restrict__ whh,
    __bf16* __restrict__ Abf, __bf16* __restrict__ Bbf)
{
    long e = ((long)blockIdx.x * blockDim.x + threadIdx.x) * 8;
    const float* p0; const float* p1; __bf16* dst; long eo;
    if (e < TOTA) { p0 = x;   p1 = h;   dst = Abf; eo = e; }
    else          { p0 = wih; p1 = whh; dst = Bbf; eo = e - TOTA; }
    long row = eo >> 11;
    long kk  = eo & 2047;
    const float* src = (kk < 1024) ? (p0 + row * 1024 + kk)
                                   : (p1 + row * 1024 + (kk - 1024));
    float4 a = *(const float4*)(src);
    float4 b = *(const float4*)(src + 4);
    bf16x8 o;
    o[0] = (__bf16)a.x; o[1] = (__bf16)a.y; o[2] = (__bf16)a.z; o[3] = (__bf16)a.w;
    o[4] = (__bf16)b.x; o[5] = (__bf16)b.y; o[6] = (__bf16)b.z; o[7] = (__bf16)b.w;
    *(bf16x8*)(dst + eo) = o;
}

// ---------------------------------------------------------------------------
// Kernel 2: 256x256-tile 8-phase bf16 GEMM.
// R10: balanced LDS-read phases — B-fragment reads split bQ->{P1,P2},
// bP->{P5,P6} (max 8 ds_read/phase, was 12 at P3/P7); stages reordered
// B-quarters-first (P0,P1=B; P2,P3=A per K-tile); counted vmcnt re-derived
// by exact FIFO simulation: P1:6, P3:8, P5:6, P7:8 (last iter 4/2/0/0).
// Every drain targets loads >=4 phases old; A-read schedule unchanged.
// 1 block/CU (unified reg need ~244; see R8 post-mortem — do NOT raise
// launch_bounds min-waves).
// ---------------------------------------------------------------------------
__device__ inline void gload_lds16(const void* g, void* l) {
    __builtin_amdgcn_global_load_lds(
        (const __attribute__((address_space(1))) void*)g,
        (__attribute__((address_space(3))) void*)l, 16, 0, 0);
}

#define WAIT_VM(n) asm volatile("s_waitcnt vmcnt(" #n ")" ::: "memory")
#define BARRIER()  __builtin_amdgcn_s_barrier()

template<int Q>
__device__ inline void mma_q(f32x4 (&acc)[8][4],
                             const bf16x8 (&a)[2][2], const bf16x8 (&b)[4][2])
{
#pragma unroll
    for (int ks = 0; ks < 2; ++ks)          // ks OUTER: 8 indep accs per pass
#pragma unroll
        for (int u = 0; u < 2; ++u)
#pragma unroll
            for (int nf = 0; nf < 4; ++nf)
                acc[2 * Q + u][nf] = __builtin_amdgcn_mfma_f32_16x16x32_bf16(
                    a[u][ks], b[nf][ks], acc[2 * Q + u][nf], 0, 0, 0);
}

__global__ __launch_bounds__(512, 2) void gemm_8phase_kernel(
    const __bf16* __restrict__ A, const __bf16* __restrict__ Bt,
    const float* __restrict__ bias, __bf16* __restrict__ V)
{
    __shared__ __bf16 smem[2][32768];   // 128 KiB: per buf {A[256][64], B[256][64]}

    const int tid = threadIdx.x;
    const int l   = tid & 63;
    const int w   = tid >> 6;
    const int wm  = w >> 2;
    const int wn  = w & 3;
    const int lane16 = l & 15;
    const int q16    = l >> 4;

    const int bid = blockIdx.x;
    const int swz = (bid & 7) * 64 + (bid >> 3);
    const int tileN = (swz & 15) * 256;
    const int tileM = (swz >> 4) * 256;

    const int srow  = (w >> 2) * 128 + (w & 3) * 8 + (l >> 3);
    const int sgran = (l & 7) ^ (l >> 3);
    const __bf16* Asrc = A  + (long)(tileM + srow) * KDIM + sgran * 8;
    const __bf16* Bsrc = Bt + (long)(tileN + srow) * KDIM + sgran * 8;
    const int a_dst = (w >> 2) * 8192 + (w & 3) * 512;
    const int b_dst = 16384 + a_dst;

    const int g0os = ((q16 ^ (l & 7))) * 8;
    const int g1os = (((q16 + 4) ^ (l & 7))) * 8;
    const int a_rd = wm * 8192 + lane16 * 64;
    const int b_rd = 16384 + wn * 4096 + lane16 * 64;

    f32x4 acc[8][4] = {};
    bf16x8 aX[2][2], aY[2][2], bP[4][2], bQ[4][2];

    auto stageA = [&](int c, int kt, int p) {
        gload_lds16(Asrc + (long)kt * 64 + (long)p * (32 * KDIM),
                    &smem[c][a_dst + p * 2048]);
    };
    auto stageB = [&](int c, int kt, int p) {
        gload_lds16(Bsrc + (long)kt * 64 + (long)p * (32 * KDIM),
                    &smem[c][b_dst + p * 2048]);
    };
    auto readA = [&](bf16x8 (&d)[2][2], int c, int q) {
        const __bf16* base = &smem[c][a_rd + q * 2048];
#pragma unroll
        for (int u = 0; u < 2; ++u) {
            d[u][0] = *(const bf16x8*)(base + u * 1024 + g0os);
            d[u][1] = *(const bf16x8*)(base + u * 1024 + g1os);
        }
    };
    auto readBfull = [&](bf16x8 (&d)[4][2], int c) {
        const __bf16* base = &smem[c][b_rd];
#pragma unroll
        for (int nf = 0; nf < 4; ++nf) {
            d[nf][0] = *(const bf16x8*)(base + nf * 1024 + g0os);
            d[nf][1] = *(const bf16x8*)(base + nf * 1024 + g1os);
        }
    };
    auto readBh = [&](bf16x8 (&d)[4][2], int c, int hhalf) {
        const __bf16* base = &smem[c][b_rd];
#pragma unroll
        for (int k = 0; k < 2; ++k) {
            const int nf = 2 * hhalf + k;
            d[nf][0] = *(const bf16x8*)(base + nf * 1024 + g0os);
            d[nf][1] = *(const bf16x8*)(base + nf * 1024 + g1os);
        }
    };

    // ---------------- prologue: stage K-tiles 0 and 1 (B-first order) -------
#pragma unroll
    for (int p = 0; p < 4; ++p) stageB(0, 0, p);
#pragma unroll
    for (int p = 0; p < 4; ++p) stageA(0, 0, p);
#pragma unroll
    for (int p = 0; p < 4; ++p) stageB(1, 1, p);
#pragma unroll
    for (int p = 0; p < 4; ++p) stageA(1, 1, p);
    WAIT_VM(8);                  // buf0 fully landed; buf1's 8 in flight
    BARRIER();
    readBfull(bP, 0);
    readA(aX, 0, 0);
    asm volatile("s_waitcnt lgkmcnt(0)" ::: "memory");
    BARRIER();

    // ---------------- main loop: 8 phases per 2 K-tiles ----------------
    // Per-iter stage order (2 gload/phase): P0,P1: B(k0+2) q01,q23;
    // P2,P3: A(k0+2) q01,q23; P4,P5: B(k1+2); P6,P7: A(k1+2).
#pragma unroll 1
    for (int i = 0; i < NT / 2; ++i) {
        const int k0 = 2 * i;
        const int k1 = 2 * i + 1;
        const bool st = (i < NT / 2 - 1);

        // P0: read aY q1 | stage B(k0+2) q0,q1
        readA(aY, 0, 1);
        if (st) { stageB(0, k0 + 2, 0); stageB(0, k0 + 2, 1); }
        BARRIER();
        __builtin_amdgcn_s_setprio(1); mma_q<0>(acc, aX, bP); __builtin_amdgcn_s_setprio(0);

        // P1: drain {A(k0)q23, B(k1)q0-3} | read aX q2 + bQ half0 | stage B q2,q3
        if (st) { WAIT_VM(6); } else { WAIT_VM(4); }
        readA(aX, 0, 2);
        readBh(bQ, 1, 0);
        if (st) { stageB(0, k0 + 2, 2); stageB(0, k0 + 2, 3); }
        BARRIER();
        __builtin_amdgcn_s_setprio(1); mma_q<1>(acc, aY, bP); __builtin_amdgcn_s_setprio(0);

        // P2: read aY q3 + bQ half1 | stage A(k0+2) q0,q1
        readA(aY, 0, 3);
        readBh(bQ, 1, 1);
        if (st) { stageA(0, k0 + 2, 0); stageA(0, k0 + 2, 1); }
        BARRIER();
        __builtin_amdgcn_s_setprio(1); mma_q<2>(acc, aX, bP); __builtin_amdgcn_s_setprio(0);

        // P3: drain A(k1) q0,q1 | read aX(buf1 q0) | stage A q2,q3
        if (st) { WAIT_VM(8); } else { WAIT_VM(2); }
        readA(aX, 1, 0);
        if (st) { stageA(0, k0 + 2, 2); stageA(0, k0 + 2, 3); }
        BARRIER();
        __builtin_amdgcn_s_setprio(1); mma_q<3>(acc, aY, bP); __builtin_amdgcn_s_setprio(0);

        // P4: read aY(buf1 q1) | stage B(k1+2) q0,q1
        readA(aY, 1, 1);
        if (st) { stageB(1, k1 + 2, 0); stageB(1, k1 + 2, 1); }
        BARRIER();
        __builtin_amdgcn_s_setprio(1); mma_q<0>(acc, aX, bQ); __builtin_amdgcn_s_setprio(0);

        // P5: drain {A(k1)q23, B(k0+2)q0-3} | read aX q2 + bP half0 | stage B q2,q3
        if (st) { WAIT_VM(6); } else { WAIT_VM(0); }
        readA(aX, 1, 2);
        if (st) readBh(bP, 0, 0);
        if (st) { stageB(1, k1 + 2, 2); stageB(1, k1 + 2, 3); }
        BARRIER();
        __builtin_amdgcn_s_setprio(1); mma_q<1>(acc, aY, bQ); __builtin_amdgcn_s_setprio(0);

        // P6: read aY q3 + bP half1 | stage A(k1+2) q0,q1
        readA(aY, 1, 3);
        if (st) readBh(bP, 0, 1);
        if (st) { stageA(1, k1 + 2, 0); stageA(1, k1 + 2, 1); }
        BARRIER();
        __builtin_amdgcn_s_setprio(1); mma_q<2>(acc, aX, bQ); __builtin_amdgcn_s_setprio(0);

        // P7: drain A(k0+2) q0,q1 | read aX(buf0 q0) | stage A q2,q3
        if (st) {
            WAIT_VM(8);
            readA(aX, 0, 0);
            stageA(1, k1 + 2, 2); stageA(1, k1 + 2, 3);
        }
        BARRIER();
        __builtin_amdgcn_s_setprio(1); mma_q<3>(acc, aY, bQ); __builtin_amdgcn_s_setprio(0);
    }

    // ---------------- epilogue: V = bf16(acc + bias) ----------------
#pragma unroll
    for (int mi = 0; mi < 8; ++mi) {
        const int row = tileM + wm * 128 + mi * 16 + q16 * 4;
#pragma unroll
        for (int ni = 0; ni < 4; ++ni) {
            const int col = tileN + wn * 64 + ni * 16 + lane16;
            const float bv = bias[col];
#pragma unroll
            for (int j = 0; j < 4; ++j)
                V[(long)(row + j) * NDIM + col] = (__bf16)(acc[mi][ni][j] + bv);
        }
    }
}

// ---------------------------------------------------------------------------
// Kernel 3: per-row fused LayerNorm + LSTM cell (v bf16).
// ---------------------------------------------------------------------------
__device__ inline float sigm_(float x) { return 1.f / (1.f + __expf(-x)); }
__device__ inline float tanh_(float x) { float e = __expf(2.f * x); return 1.f - 2.f / (e + 1.f); }

__global__ __launch_bounds__(256) void ln_lstm_kernel(
    const __bf16* __restrict__ v, const float* __restrict__ cin,
    const float* __restrict__ gamma4, const float* __restrict__ beta4,
    const float* __restrict__ gammac, const float* __restrict__ betac,
    float* __restrict__ out_h, float* __restrict__ out_c)
{
    __shared__ float gbuf[4][1024];
    __shared__ float red[8];

    const int b = blockIdx.x;
    const int t = threadIdx.x;
    const int w = t >> 6;
    const int l = t & 63;

    const __bf16* vb = v + (long)b * 4096 + w * 1024 + l * 16;
    bf16x8 v0 = *(const bf16x8*)(vb);
    bf16x8 v1 = *(const bf16x8*)(vb + 8);
    float xs[16];
#pragma unroll
    for (int q = 0; q < 8; ++q) { xs[q] = (float)v0[q]; xs[8 + q] = (float)v1[q]; }

    float s = 0.f, sq = 0.f;
#pragma unroll
    for (int q = 0; q < 16; ++q) { s += xs[q]; sq += xs[q] * xs[q]; }
#pragma unroll
    for (int m = 32; m >= 1; m >>= 1) { s += __shfl_xor(s, m); sq += __shfl_xor(sq, m); }

    const float mean = s * (1.f / 1024.f);
    const float var  = (sq - s * mean) * (1.f / 1023.f);
    const float invd = 1.f / (sqrtf(var) + LN_EPS);

#pragma unroll
    for (int q = 0; q < 16; ++q) {
        const int idx = l * 16 + q;
        gbuf[w][idx] = gamma4[w * 1024 + idx] * (xs[q] - mean) * invd + beta4[w * 1024 + idx];
    }
    __syncthreads();

    const int j0 = t * 4;
    float4 iv = *(const float4*)&gbuf[0][j0];
    float4 fv = *(const float4*)&gbuf[1][j0];
    float4 gv = *(const float4*)&gbuf[2][j0];
    float4 ov = *(const float4*)&gbuf[3][j0];
    float4 cv = *(const float4*)(cin + (long)b * 1024 + j0);

    float nc[4], oo[4];
    {
        const float ia[4] = {iv.x, iv.y, iv.z, iv.w};
        const float fa[4] = {fv.x, fv.y, fv.z, fv.w};
        const float ga[4] = {gv.x, gv.y, gv.z, gv.w};
        const float oa[4] = {ov.x, ov.y, ov.z, ov.w};
        const float ca[4] = {cv.x, cv.y, cv.z, cv.w};
#pragma unroll
        for (int q = 0; q < 4; ++q) {
            nc[q] = ca[q] * sigm_(fa[q] + 1.f) + sigm_(ia[q]) * tanh_(ga[q]);
            oo[q] = oa[q];
        }
    }

    float s2 = 0.f, sq2 = 0.f;
#pragma unroll
    for (int q = 0; q < 4; ++q) { s2 += nc[q]; sq2 += nc[q] * nc[q]; }
#pragma unroll
    for (int m = 32; m >= 1; m >>= 1) { s2 += __shfl_xor(s2, m); sq2 += __shfl_xor(sq2, m); }
    if (l == 0) { red[w] = s2; red[4 + w] = sq2; }
    __syncthreads();
    const float S  = red[0] + red[1] + red[2] + red[3];
    const float SQ = red[4] + red[5] + red[6] + red[7];
    const float mean2 = S * (1.f / 1024.f);
    const float var2  = (SQ - S * mean2) * (1.f / 1023.f);
    const float invd2 = 1.f / (sqrtf(var2) + LN_EPS);

    float4 hout, cout;
    float ho[4], co[4];
#pragma unroll
    for (int q = 0; q < 4; ++q) {
        const int j = j0 + q;
        const float ncl = gammac[j] * (nc[q] - mean2) * invd2 + betac[j];
        co[q] = ncl;
        ho[q] = tanh_(ncl) * sigm_(oo[q]);
    }
    hout.x = ho[0]; hout.y = ho[1]; hout.z = ho[2]; hout.w = ho[3];
    cout.x = co[0]; cout.y = co[1]; cout.z = co[2]; cout.w = co[3];
    *(float4*)(out_h + (long)b * 1024 + j0) = hout;
    *(float4*)(out_c + (long)b * 1024 + j0) = cout;
}

// ---------------------------------------------------------------------------
extern "C" void kernel_launch(void* const* d_in, const int* in_sizes, int n_in,
                              void* d_out, int out_size, void* d_ws, size_t ws_size,
                              hipStream_t stream)
{
    const float* x      = (const float*)d_in[0];
    const float* h      = (const float*)d_in[1];
    const float* c      = (const float*)d_in[2];
    const float* w_ih   = (const float*)d_in[3];
    const float* b_ih   = (const float*)d_in[4];
    const float* w_hh   = (const float*)d_in[5];
    const float* gamma4 = (const float*)d_in[6];
    const float* beta4  = (const float*)d_in[7];
    const float* gammac = (const float*)d_in[8];
    const float* betac  = (const float*)d_in[9];

    char* ws = (char*)d_ws;
    const size_t szA = (size_t)BDIM * KDIM * 2;
    const size_t szB = (size_t)NDIM * KDIM * 2;
    const size_t szV = (size_t)BDIM * NDIM * 2;
    if (ws_size < szA + szB + szV) return;

    __bf16* Abf = (__bf16*)ws;
    __bf16* Bbf = (__bf16*)(ws + szA);
    __bf16* v   = (__bf16*)(ws + szA + szB);

    float* out_h = (float*)d_out;
    float* out_c = out_h + (size_t)BDIM * HDIM;

    cvt_all_kernel<<<dim3((unsigned)((TOTA + TOTB) / 8 / 256)), dim3(256), 0, stream>>>(
        x, h, w_ih, w_hh, Abf, Bbf);

    gemm_8phase_kernel<<<dim3((BDIM / 256) * (NDIM / 256)), dim3(512), 0, stream>>>(
        Abf, Bbf, b_ih, v);

    ln_lstm_kernel<<<dim3(BDIM), dim3(256), 0, stream>>>(
        v, c, gamma4, beta4, gammac, betac, out_h, out_c);
}

// Round 11
// 193.658 us; speedup vs baseline: 1.0243x; 1.0243x over previous
//
#include <hip/hip_runtime.h>
#include <hip/hip_bf16.h>
#include <cstdint>

typedef __bf16 bf16x8 __attribute__((ext_vector_type(8)));
typedef float  f32x4  __attribute__((ext_vector_type(4)));

#define BDIM 8192
#define KDIM 2048
#define NDIM 4096
#define HDIM 1024
#define LN_EPS 1e-6f
#define NT    (KDIM / 64)    // 32 K-tiles of BK=64
#define TOTA  ((long)BDIM * KDIM)
#define TOTB  ((long)NDIM * KDIM)

// ---------------------------------------------------------------------------
// Kernel 1: merged f32 -> bf16 convert + concat for A=[x|h] and Bt=[w_ih|w_hh].
// ---------------------------------------------------------------------------
__global__ __launch_bounds__(256) void cvt_all_kernel(
    const float* __restrict__ x, const float* __restrict__ h,
    const float* __restrict__ wih, const float* __restrict__ whh,
    __bf16* __restrict__ Abf, __bf16* __restrict__ Bbf)
{
    long e = ((long)blockIdx.x * blockDim.x + threadIdx.x) * 8;
    const float* p0; const float* p1; __bf16* dst; long eo;
    if (e < TOTA) { p0 = x;   p1 = h;   dst = Abf; eo = e; }
    else          { p0 = wih; p1 = whh; dst = Bbf; eo = e - TOTA; }
    long row = eo >> 11;
    long kk  = eo & 2047;
    const float* src = (kk < 1024) ? (p0 + row * 1024 + kk)
                                   : (p1 + row * 1024 + (kk - 1024));
    float4 a = *(const float4*)(src);
    float4 b = *(const float4*)(src + 4);
    bf16x8 o;
    o[0] = (__bf16)a.x; o[1] = (__bf16)a.y; o[2] = (__bf16)a.z; o[3] = (__bf16)a.w;
    o[4] = (__bf16)b.x; o[5] = (__bf16)b.y; o[6] = (__bf16)b.z; o[7] = (__bf16)b.w;
    *(bf16x8*)(dst + eo) = o;
}

// ---------------------------------------------------------------------------
// Kernel 2: 256x256-tile bf16 GEMM — R11: barrier-thinned 4-superphase loop.
// Superphase = {readA(next); BARRIER; mma<even>; stages; [VM/readB]; readA; mma<odd>}.
// All stages post-barrier: each stage's target readers are exactly one barrier
// behind (same >=500cyc DMA vs <=150cyc read-retire margin as R5/R6).
// vmcnt FIFO order identical to R9: VM(6) drains prev-iter's 8 buf-stages.
// Register ping-pong aX/aY, bP/bQ unchanged -> no extra VGPRs (R8 lesson:
// unified reg need ~244; never raise launch_bounds min-waves).
// ---------------------------------------------------------------------------
__device__ inline void gload_lds16(const void* g, void* l) {
    __builtin_amdgcn_global_load_lds(
        (const __attribute__((address_space(1))) void*)g,
        (__attribute__((address_space(3))) void*)l, 16, 0, 0);
}

#define WAIT_VM(n) asm volatile("s_waitcnt vmcnt(" #n ")" ::: "memory")
#define BARRIER()  __builtin_amdgcn_s_barrier()

template<int Q>
__device__ inline void mma_q(f32x4 (&acc)[8][4],
                             const bf16x8 (&a)[2][2], const bf16x8 (&b)[4][2])
{
#pragma unroll
    for (int ks = 0; ks < 2; ++ks)          // ks OUTER: 8 indep accs per pass
#pragma unroll
        for (int u = 0; u < 2; ++u)
#pragma unroll
            for (int nf = 0; nf < 4; ++nf)
                acc[2 * Q + u][nf] = __builtin_amdgcn_mfma_f32_16x16x32_bf16(
                    a[u][ks], b[nf][ks], acc[2 * Q + u][nf], 0, 0, 0);
}

__global__ __launch_bounds__(512, 2) void gemm_8phase_kernel(
    const __bf16* __restrict__ A, const __bf16* __restrict__ Bt,
    const float* __restrict__ bias, __bf16* __restrict__ V)
{
    __shared__ __bf16 smem[2][32768];   // 128 KiB: per buf {A[256][64], B[256][64]}

    const int tid = threadIdx.x;
    const int l   = tid & 63;
    const int w   = tid >> 6;
    const int wm  = w >> 2;
    const int wn  = w & 3;
    const int lane16 = l & 15;
    const int q16    = l >> 4;

    const int bid = blockIdx.x;
    const int swz = (bid & 7) * 64 + (bid >> 3);
    const int tileN = (swz & 15) * 256;
    const int tileM = (swz >> 4) * 256;

    const int srow  = (w >> 2) * 128 + (w & 3) * 8 + (l >> 3);
    const int sgran = (l & 7) ^ (l >> 3);
    const __bf16* Asrc = A  + (long)(tileM + srow) * KDIM + sgran * 8;
    const __bf16* Bsrc = Bt + (long)(tileN + srow) * KDIM + sgran * 8;
    const int a_dst = (w >> 2) * 8192 + (w & 3) * 512;
    const int b_dst = 16384 + a_dst;

    const int g0os = ((q16 ^ (l & 7))) * 8;
    const int g1os = (((q16 + 4) ^ (l & 7))) * 8;
    const int a_rd = wm * 8192 + lane16 * 64;
    const int b_rd = 16384 + wn * 4096 + lane16 * 64;

    f32x4 acc[8][4] = {};
    bf16x8 aX[2][2], aY[2][2], bP[4][2], bQ[4][2];

    auto stageA = [&](int c, int kt, int p) {
        gload_lds16(Asrc + (long)kt * 64 + (long)p * (32 * KDIM),
                    &smem[c][a_dst + p * 2048]);
    };
    auto stageB = [&](int c, int kt, int p) {
        gload_lds16(Bsrc + (long)kt * 64 + (long)p * (32 * KDIM),
                    &smem[c][b_dst + p * 2048]);
    };
    auto readA = [&](bf16x8 (&d)[2][2], int c, int q) {
        const __bf16* base = &smem[c][a_rd + q * 2048];
#pragma unroll
        for (int u = 0; u < 2; ++u) {
            d[u][0] = *(const bf16x8*)(base + u * 1024 + g0os);
            d[u][1] = *(const bf16x8*)(base + u * 1024 + g1os);
        }
    };
    auto readB = [&](bf16x8 (&d)[4][2], int c) {
        const __bf16* base = &smem[c][b_rd];
#pragma unroll
        for (int nf = 0; nf < 4; ++nf) {
            d[nf][0] = *(const bf16x8*)(base + nf * 1024 + g0os);
            d[nf][1] = *(const bf16x8*)(base + nf * 1024 + g1os);
        }
    };

    // ---------------- prologue: stage K-tiles 0 and 1 ----------------
#pragma unroll
    for (int p = 0; p < 4; ++p) { stageA(0, 0, p); stageB(0, 0, p); }
#pragma unroll
    for (int p = 0; p < 4; ++p) { stageA(1, 1, p); stageB(1, 1, p); }
    WAIT_VM(8);
    BARRIER();
    readB(bP, 0);
    readA(aX, 0, 0);
    asm volatile("s_waitcnt lgkmcnt(0)" ::: "memory");
    BARRIER();

    // ------------- main loop: 4 superphases per 2 K-tiles -------------
#pragma unroll 1
    for (int i = 0; i < NT / 2; ++i) {
        const int k0 = 2 * i;
        const int k1 = 2 * i + 1;
        const bool st = (i < NT / 2 - 1);

        // S0: q0,q1 of k0
        readA(aY, 0, 1);
        BARRIER();
        __builtin_amdgcn_s_setprio(1); mma_q<0>(acc, aX, bP); __builtin_amdgcn_s_setprio(0);
        if (st) { stageA(0, k0 + 2, 0); stageB(0, k0 + 2, 0); }
        readA(aX, 0, 2);
        if (st) { stageA(0, k0 + 2, 1); stageB(0, k0 + 2, 1); }
        __builtin_amdgcn_s_setprio(1); mma_q<1>(acc, aY, bP); __builtin_amdgcn_s_setprio(0);

        // S1: q2,q3 of k0; drain k1's stages; read k1 frags
        readA(aY, 0, 3);
        BARRIER();
        __builtin_amdgcn_s_setprio(1); mma_q<2>(acc, aX, bP); __builtin_amdgcn_s_setprio(0);
        if (st) { stageA(0, k0 + 2, 2); stageB(0, k0 + 2, 2); }
        if (st) { WAIT_VM(6); } else { WAIT_VM(0); }
        readB(bQ, 1);
        readA(aX, 1, 0);
        if (st) { stageA(0, k0 + 2, 3); stageB(0, k0 + 2, 3); }
        __builtin_amdgcn_s_setprio(1); mma_q<3>(acc, aY, bP); __builtin_amdgcn_s_setprio(0);

        // S2: q0,q1 of k1
        readA(aY, 1, 1);
        BARRIER();
        __builtin_amdgcn_s_setprio(1); mma_q<0>(acc, aX, bQ); __builtin_amdgcn_s_setprio(0);
        if (st) { stageA(1, k1 + 2, 0); stageB(1, k1 + 2, 0); }
        readA(aX, 1, 2);
        if (st) { stageA(1, k1 + 2, 1); stageB(1, k1 + 2, 1); }
        __builtin_amdgcn_s_setprio(1); mma_q<1>(acc, aY, bQ); __builtin_amdgcn_s_setprio(0);

        // S3: q2,q3 of k1; drain k0+2's stages; read its frags
        readA(aY, 1, 3);
        BARRIER();
        __builtin_amdgcn_s_setprio(1); mma_q<2>(acc, aX, bQ); __builtin_amdgcn_s_setprio(0);
        if (st) {
            stageA(1, k1 + 2, 2); stageB(1, k1 + 2, 2);
            WAIT_VM(6);
            readB(bP, 0);
            readA(aX, 0, 0);
            stageA(1, k1 + 2, 3); stageB(1, k1 + 2, 3);
        }
        __builtin_amdgcn_s_setprio(1); mma_q<3>(acc, aY, bQ); __builtin_amdgcn_s_setprio(0);
    }

    // ---------------- epilogue: V = bf16(acc + bias) ----------------
#pragma unroll
    for (int mi = 0; mi < 8; ++mi) {
        const int row = tileM + wm * 128 + mi * 16 + q16 * 4;
#pragma unroll
        for (int ni = 0; ni < 4; ++ni) {
            const int col = tileN + wn * 64 + ni * 16 + lane16;
            const float bv = bias[col];
#pragma unroll
            for (int j = 0; j < 4; ++j)
                V[(long)(row + j) * NDIM + col] = (__bf16)(acc[mi][ni][j] + bv);
        }
    }
}

// ---------------------------------------------------------------------------
// Kernel 3: per-row fused LayerNorm + LSTM cell (v bf16).
// ---------------------------------------------------------------------------
__device__ inline float sigm_(float x) { return 1.f / (1.f + __expf(-x)); }
__device__ inline float tanh_(float x) { float e = __expf(2.f * x); return 1.f - 2.f / (e + 1.f); }

__global__ __launch_bounds__(256) void ln_lstm_kernel(
    const __bf16* __restrict__ v, const float* __restrict__ cin,
    const float* __restrict__ gamma4, const float* __restrict__ beta4,
    const float* __restrict__ gammac, const float* __restrict__ betac,
    float* __restrict__ out_h, float* __restrict__ out_c)
{
    __shared__ float gbuf[4][1024];
    __shared__ float red[8];

    const int b = blockIdx.x;
    const int t = threadIdx.x;
    const int w = t >> 6;
    const int l = t & 63;

    const __bf16* vb = v + (long)b * 4096 + w * 1024 + l * 16;
    bf16x8 v0 = *(const bf16x8*)(vb);
    bf16x8 v1 = *(const bf16x8*)(vb + 8);
    float xs[16];
#pragma unroll
    for (int q = 0; q < 8; ++q) { xs[q] = (float)v0[q]; xs[8 + q] = (float)v1[q]; }

    float s = 0.f, sq = 0.f;
#pragma unroll
    for (int q = 0; q < 16; ++q) { s += xs[q]; sq += xs[q] * xs[q]; }
#pragma unroll
    for (int m = 32; m >= 1; m >>= 1) { s += __shfl_xor(s, m); sq += __shfl_xor(sq, m); }

    const float mean = s * (1.f / 1024.f);
    const float var  = (sq - s * mean) * (1.f / 1023.f);
    const float invd = 1.f / (sqrtf(var) + LN_EPS);

#pragma unroll
    for (int q = 0; q < 16; ++q) {
        const int idx = l * 16 + q;
        gbuf[w][idx] = gamma4[w * 1024 + idx] * (xs[q] - mean) * invd + beta4[w * 1024 + idx];
    }
    __syncthreads();

    const int j0 = t * 4;
    float4 iv = *(const float4*)&gbuf[0][j0];
    float4 fv = *(const float4*)&gbuf[1][j0];
    float4 gv = *(const float4*)&gbuf[2][j0];
    float4 ov = *(const float4*)&gbuf[3][j0];
    float4 cv = *(const float4*)(cin + (long)b * 1024 + j0);

    float nc[4], oo[4];
    {
        const float ia[4] = {iv.x, iv.y, iv.z, iv.w};
        const float fa[4] = {fv.x, fv.y, fv.z, fv.w};
        const float ga[4] = {gv.x, gv.y, gv.z, gv.w};
        const float oa[4] = {ov.x, ov.y, ov.z, ov.w};
        const float ca[4] = {cv.x, cv.y, cv.z, cv.w};
#pragma unroll
        for (int q = 0; q < 4; ++q) {
            nc[q] = ca[q] * sigm_(fa[q] + 1.f) + sigm_(ia[q]) * tanh_(ga[q]);
            oo[q] = oa[q];
        }
    }

    float s2 = 0.f, sq2 = 0.f;
#pragma unroll
    for (int q = 0; q < 4; ++q) { s2 += nc[q]; sq2 += nc[q] * nc[q]; }
#pragma unroll
    for (int m = 32; m >= 1; m >>= 1) { s2 += __shfl_xor(s2, m); sq2 += __shfl_xor(sq2, m); }
    if (l == 0) { red[w] = s2; red[4 + w] = sq2; }
    __syncthreads();
    const float S  = red[0] + red[1] + red[2] + red[3];
    const float SQ = red[4] + red[5] + red[6] + red[7];
    const float mean2 = S * (1.f / 1024.f);
    const float var2  = (SQ - S * mean2) * (1.f / 1023.f);
    const float invd2 = 1.f / (sqrtf(var2) + LN_EPS);

    float4 hout, cout;
    float ho[4], co[4];
#pragma unroll
    for (int q = 0; q < 4; ++q) {
        const int j = j0 + q;
        const float ncl = gammac[j] * (nc[q] - mean2) * invd2 + betac[j];
        co[q] = ncl;
        ho[q] = tanh_(ncl) * sigm_(oo[q]);
    }
    hout.x = ho[0]; hout.y = ho[1]; hout.z = ho[2]; hout.w = ho[3];
    cout.x = co[0]; cout.y = co[1]; cout.z = co[2]; cout.w = co[3];
    *(float4*)(out_h + (long)b * 1024 + j0) = hout;
    *(float4*)(out_c + (long)b * 1024 + j0) = cout;
}

// ---------------------------------------------------------------------------
extern "C" void kernel_launch(void* const* d_in, const int* in_sizes, int n_in,
                              void* d_out, int out_size, void* d_ws, size_t ws_size,
                              hipStream_t stream)
{
    const float* x      = (const float*)d_in[0];
    const float* h      = (const float*)d_in[1];
    const float* c      = (const float*)d_in[2];
    const float* w_ih   = (const float*)d_in[3];
    const float* b_ih   = (const float*)d_in[4];
    const float* w_hh   = (const float*)d_in[5];
    const float* gamma4 = (const float*)d_in[6];
    const float* beta4  = (const float*)d_in[7];
    const float* gammac = (const float*)d_in[8];
    const float* betac  = (const float*)d_in[9];

    char* ws = (char*)d_ws;
    const size_t szA = (size_t)BDIM * KDIM * 2;
    const size_t szB = (size_t)NDIM * KDIM * 2;
    const size_t szV = (size_t)BDIM * NDIM * 2;
    if (ws_size < szA + szB + szV) return;

    __bf16* Abf = (__bf16*)ws;
    __bf16* Bbf = (__bf16*)(ws + szA);
    __bf16* v   = (__bf16*)(ws + szA + szB);

    float* out_h = (float*)d_out;
    float* out_c = out_h + (size_t)BDIM * HDIM;

    cvt_all_kernel<<<dim3((unsigned)((TOTA + TOTB) / 8 / 256)), dim3(256), 0, stream>>>(
        x, h, w_ih, w_hh, Abf, Bbf);

    gemm_8phase_kernel<<<dim3((BDIM / 256) * (NDIM / 256)), dim3(512), 0, stream>>>(
        Abf, Bbf, b_ih, v);

    ln_lstm_kernel<<<dim3(BDIM), dim3(256), 0, stream>>>(
        v, c, gamma4, beta4, gammac, betac, out_h, out_c);
}